// Round 9
// baseline (280.418 us; speedup 1.0000x reference)
//
#include <hip/hip_runtime.h>

#define NG   256   // graphs (= grid)
#define NP   512   // nodes per graph
#define EPG  8192  // edges per graph
#define FDIM 128
#define STB  36    // bufB stride (floats): 144 B, 16B-aligned; random-row b128 gather at its throughput floor

// ---- LDS layout (bytes) ----
#define OFF_STAGE 0                        // x chunk stage: 512 rows x 128 B = 65536; later h1 archive [16 pairs][512] float2
#define OFF_BUFB  65536                    // f32[512*36] = 73728 -> ends 139264
#define OFF_CSR   139264                   // u16[8192] = 16384 -> 155648
#define OFF_OFFS  155648                   // u16[513] -> 1032  -> 156680
#define OFF_WT    156680                   // u32[8] = 32       -> 156712
#define OFF_CUR   156712                   // u32[512] = 2048   -> 158760 (lin3S overlay later)
#define OFF_PAD   158760                   // 8 B pad
#define OFF_DCNT  158768                   // u32[512] = 2048   -> 160816
#define OFF_NRM   160816                   // f32[512] = 2048   -> 162864 (keyA overlay after h4)
#define OFF_BINS  162864                   // u32[96]: [0..47] counts, [48..95] excl offsets -> 163248
#define SMEM_SZ   163248                   // <= 163840

// overlays
#define OFF_L3    OFF_CUR                  // f32[512] lin3S (cursors dead after CSR build)
#define OFF_PERM  OFF_DCNT                 // u16[512] degree-balanced perm (dcnt dead after PH2a)
#define OFF_KEY   OFF_NRM                  // f32[512] keyA (each slot read-own-then-write-own in h4)
#define OFF_RANKP OFF_CSR                  // u16[1024] (csr dead after h4 agg)
#define OFF_TIDX  (OFF_CSR + 2048)         // u16[64] (pad to 256)
#define OFF_TKEY  (OFF_CSR + 2304)         // f32[64]
// tail arrays overlay bufB (h3 consumed by fused gather before overwrite); float offsets
// featS transposed: [64 nodes][100 floats] (stride 100 = 400 B, 16B-aligned rows; 8 start groups)
#define FO_FEAT 0                          // f32[64*100] = 6400 floats
#define FO_P    6400                       // f32[16*32]
#define FO_C2   6912                       // f32[896]
#define FO_HID  7808                       // f32[128]

__global__ __launch_bounds__(1024, 4) void dgcnn_fused(
    const float* __restrict__ x,
    const float* __restrict__ W0, const float* __restrict__ b0,
    const float* __restrict__ W1, const float* __restrict__ b1,
    const float* __restrict__ W2, const float* __restrict__ b2,
    const float* __restrict__ W3, const float* __restrict__ b3,
    const float* __restrict__ c1w, const float* __restrict__ c1b,
    const float* __restrict__ c2w, const float* __restrict__ c2b,
    const float* __restrict__ d1w, const float* __restrict__ d1b,
    const float* __restrict__ d2w, const float* __restrict__ d2b,
    const int* __restrict__ esrc, const int* __restrict__ edst,
    float* __restrict__ hs2,
    float* __restrict__ out)
{
  extern __shared__ char smem[];
  float*          stageF = (float*)(smem + OFF_STAGE);
  float2*         stage2 = (float2*)(smem + OFF_STAGE);   // h1 archive pair view
  float*          bufB  = (float*)(smem + OFF_BUFB);
  unsigned short* csr   = (unsigned short*)(smem + OFF_CSR);
  unsigned short* offs  = (unsigned short*)(smem + OFF_OFFS);
  unsigned int*   wt    = (unsigned int*)(smem + OFF_WT);
  unsigned int*   cur   = (unsigned int*)(smem + OFF_CUR);
  unsigned int*   dcnt  = (unsigned int*)(smem + OFF_DCNT);
  float*          nrm   = (float*)(smem + OFF_NRM);
  unsigned int*   bins  = (unsigned int*)(smem + OFF_BINS);
  unsigned short* perm  = (unsigned short*)(smem + OFF_PERM);
  float*          lin3S = (float*)(smem + OFF_L3);
  float*          keyA  = (float*)(smem + OFF_KEY);
  unsigned short* rankP = (unsigned short*)(smem + OFF_RANKP);
  unsigned short* topIdx= (unsigned short*)(smem + OFF_TIDX);
  float*          topKey= (float*)(smem + OFF_TKEY);

  const int g    = blockIdx.x;
  const int tid  = threadIdx.x;
  const int lane = tid & 63;
  const int wv   = __builtin_amdgcn_readfirstlane(tid >> 6);   // 0..15, wave-uniform
  const int half = __builtin_amdgcn_readfirstlane(tid >> 9);   // 0/1, wave-uniform
  const int v    = tid & 511;                                  // tid-keyed node (lin/archive-read/gather)
  const int nb   = g * NP;

  // x chunk loaders: chunk kc = dims [kc*32, kc*32+32) for all 512 rows.
  const int ldRow0 = tid >> 3;
  const int ldGrp  = tid & 7;
  const int ldSwz  = (ldGrp ^ (ldRow0 & 7)) * 16;   // row&7 invariant under +128
  auto load_chunk = [&](int kc, float4* xr) {
    const float* base = x + (size_t)nb * FDIM + kc * 32 + ldGrp * 4;
#pragma unroll
    for (int it = 0; it < 4; it++)
      xr[it] = *(const float4*)(base + (size_t)(ldRow0 + it * 128) * FDIM);
  };
  auto store_chunk = [&](const float4* xr) {
#pragma unroll
    for (int it = 0; it < 4; it++)
      *(float4*)(smem + OFF_STAGE + (ldRow0 + it * 128) * 128 + ldSwz) = xr[it];
  };

  // ---------- issue x chunk0 first (needed at first store), then edges ----------
  float4 xr[4], xr2[4];
  load_chunk(0, xr);
  const int eb = g * EPG;
  const int4* s4p = (const int4*)(esrc + eb);
  const int4* d4p = (const int4*)(edst + eb);
  const int4 sa = s4p[tid], sb = s4p[tid + 1024];
  const int4 da = d4p[tid], db = d4p[tid + 1024];

  int es[8], ed[8];
  es[0]=sa.x-nb; es[1]=sa.y-nb; es[2]=sa.z-nb; es[3]=sa.w-nb;
  es[4]=sb.x-nb; es[5]=sb.y-nb; es[6]=sb.z-nb; es[7]=sb.w-nb;
  ed[0]=da.x-nb; ed[1]=da.y-nb; ed[2]=da.z-nb; ed[3]=da.w-nb;
  ed[4]=db.x-nb; ed[5]=db.y-nb; ed[6]=db.z-nb; ed[7]=db.w-nb;

  // ---------- zero counters (ordered by S2 barrier; disjoint from stage writes) ----------
  if (tid < 512) { cur[tid] = 0u; dcnt[tid] = 0u; }
  if (tid < 96)  bins[tid] = 0u;

  // ---------- lin0 with CSR-build phases woven into chunk slots ----------
  float acc0[16];
#pragma unroll
  for (int c = 0; c < 16; c++) acc0[c] = b0[half * 16 + c];
  const char* rowp = smem + OFF_STAGE + v * 128;
  const int vswz = v & 7;
  int mydeg = 0;

  auto compute_chunk = [&](const int kc) {
#pragma unroll
    for (int jg = 0; jg < 8; jg++) {
      const float4 t = *(const float4*)(rowp + ((jg ^ vswz) * 16));
#pragma unroll
      for (int c = 0; c < 16; c++) {
        const float* wr = W0 + (size_t)(half * 16 + c) * FDIM + kc * 32 + jg * 4;
        acc0[c] = fmaf(t.x, wr[0], acc0[c]);
        acc0[c] = fmaf(t.y, wr[1], acc0[c]);
        acc0[c] = fmaf(t.z, wr[2], acc0[c]);
        acc0[c] = fmaf(t.w, wr[3], acc0[c]);
      }
    }
  };

  // ---- kc = 0 ----
  store_chunk(xr);
  load_chunk(1, xr2);
  __syncthreads();                       // S2: stage0 + zeroed counters visible
  // PH1: degree counts (edge latency hidden under chunk0 staging)
#pragma unroll
  for (int i = 0; i < 8; i++) {
    atomicAdd(&dcnt[es[i]], 1u);        // out-degree (low 16)
    atomicAdd(&dcnt[ed[i]], 65536u);    // in-degree  (high 16)
  }
  compute_chunk(0);
#pragma unroll
  for (int it = 0; it < 4; it++) xr[it] = xr2[it];
  __syncthreads();                       // S3: stage reads done, dcnt complete
  // ---- kc = 1 ----
  store_chunk(xr);
  load_chunk(2, xr2);
  __syncthreads();                       // S4: stage1 ready
  // PH2a: norm + wave-shuffle scan of in-degree
  unsigned c_scan = 0;
  if (tid < 512) {
    const unsigned cw = dcnt[tid];
    nrm[tid] = 1.0f / (float)((cw & 0xFFFFu) + 1u);
    c_scan = cw >> 16;
    mydeg = (int)(cw >> 16);
    for (int d = 1; d < 64; d <<= 1) {
      const unsigned t = __shfl_up(c_scan, (unsigned)d, 64);
      if (lane >= d) c_scan += t;
    }
    if (lane == 63) wt[wv] = c_scan;
  }
  compute_chunk(1);
#pragma unroll
  for (int it = 0; it < 4; it++) xr[it] = xr2[it];
  __syncthreads();                       // S5: stage reads done, wt visible
  // ---- kc = 2 ----
  store_chunk(xr);
  load_chunk(3, xr2);
  __syncthreads();                       // S6: stage2 ready
  // PH2b: exclusive offsets + degree-bin counts
  if (tid < 512) {
    unsigned base = 0;
    for (int w = 0; w < wv; w++) base += wt[w];
    offs[tid + 1] = (unsigned short)(base + c_scan);
    if (tid == 0) offs[0] = 0;
    const int dd = mydeg > 47 ? 47 : mydeg;
    atomicAdd(&bins[dd], 1u);
  }
  compute_chunk(2);
  __syncthreads();                       // S7: stage reads done, offs + bins visible
  // ---- kc = 3 ----
  store_chunk(xr2);
  __syncthreads();                       // S8: stage3 ready
  // PH3: fill CSR (src bucketed by dst)
#pragma unroll
  for (int i = 0; i < 8; i++) {
    const unsigned pos = (unsigned)offs[ed[i]] + atomicAdd(&cur[ed[i]], 1u);
    csr[pos] = (unsigned short)es[i];
  }
  // bin exclusive scan (wave 15; bins counted complete since S7)
  if (wv == 15) {
    const unsigned bc = (lane < 48) ? bins[lane] : 0u;
    unsigned sc = bc;
    for (int d = 1; d < 64; d <<= 1) {
      const unsigned t2 = __shfl_up(sc, (unsigned)d, 64);
      if (lane >= d) sc += t2;
    }
    if (lane < 48) bins[48 + lane] = sc - bc;   // exclusive offset
  }
  compute_chunk(3);
  {
    float4* br = (float4*)(bufB + v * STB + half * 16);
#pragma unroll
    for (int j = 0; j < 4; j++)
      br[j] = make_float4(acc0[j*4+0], acc0[j*4+1], acc0[j*4+2], acc0[j*4+3]);
  }
  __syncthreads();                       // S9: csr + bufB(z0) + bin offsets complete

  // ---------- degree-balanced permutation: thread i <-> node perm[i]; waves get uniform degree ----------
  if (tid < 512) {
    const int dd = mydeg > 47 ? 47 : mydeg;
    const unsigned c = atomicSub(&bins[dd], 1u);        // returns old count
    perm[bins[48 + dd] + c - 1u] = (unsigned short)tid; // bijective placement
  }
  __syncthreads();                       // S9b: perm complete
  const int u = (int)perm[v];            // agg-keyed node (both halves of a node read same slot)

  // aggregate own half (16 ch) for node u: h = tanh(nrm * (self + sum_neigh))
  // 4-row batching + csr index software-pipeline; per-node add order identical to round-4..8.
  float h[16];
  auto do_agg = [&]() {
    float4 A0, A1, A2, A3;
    const float4* sr = (const float4*)(bufB + u * STB + half * 16);
    A0 = sr[0]; A1 = sr[1]; A2 = sr[2]; A3 = sr[3];
    const int e0 = offs[u], e1 = offs[u + 1];
    int e = e0;
    int sc0 = 0, sc1 = 0, sc2 = 0, sc3 = 0;
    if (e + 3 < e1) { sc0 = csr[e]; sc1 = csr[e+1]; sc2 = csr[e+2]; sc3 = csr[e+3]; }
    while (e + 3 < e1) {
      const int s0 = sc0, s1 = sc1, s2 = sc2, s3 = sc3;
      const int en = e + 4;
      if (en + 3 < e1) { sc0 = csr[en]; sc1 = csr[en+1]; sc2 = csr[en+2]; sc3 = csr[en+3]; }
      const float4* rb0 = (const float4*)(bufB + s0 * STB + half * 16);
      const float4* rb1 = (const float4*)(bufB + s1 * STB + half * 16);
      const float4* rb2 = (const float4*)(bufB + s2 * STB + half * 16);
      const float4* rb3 = (const float4*)(bufB + s3 * STB + half * 16);
      const float4 p0 = rb0[0], p1 = rb0[1], p2 = rb0[2], p3 = rb0[3];
      const float4 q0 = rb1[0], q1 = rb1[1], q2 = rb1[2], q3 = rb1[3];
      const float4 r0 = rb2[0], r1 = rb2[1], r2 = rb2[2], r3 = rb2[3];
      const float4 t0 = rb3[0], t1 = rb3[1], t2 = rb3[2], t3 = rb3[3];
      // pair 1
      A0.x += p0.x + q0.x; A0.y += p0.y + q0.y; A0.z += p0.z + q0.z; A0.w += p0.w + q0.w;
      A1.x += p1.x + q1.x; A1.y += p1.y + q1.y; A1.z += p1.z + q1.z; A1.w += p1.w + q1.w;
      A2.x += p2.x + q2.x; A2.y += p2.y + q2.y; A2.z += p2.z + q2.z; A2.w += p2.w + q2.w;
      A3.x += p3.x + q3.x; A3.y += p3.y + q3.y; A3.z += p3.z + q3.z; A3.w += p3.w + q3.w;
      // pair 2
      A0.x += r0.x + t0.x; A0.y += r0.y + t0.y; A0.z += r0.z + t0.z; A0.w += r0.w + t0.w;
      A1.x += r1.x + t1.x; A1.y += r1.y + t1.y; A1.z += r1.z + t1.z; A1.w += r1.w + t1.w;
      A2.x += r2.x + t2.x; A2.y += r2.y + t2.y; A2.z += r2.z + t2.z; A2.w += r2.w + t2.w;
      A3.x += r3.x + t3.x; A3.y += r3.y + t3.y; A3.z += r3.z + t3.z; A3.w += r3.w + t3.w;
      e = en;
    }
    for (; e + 1 < e1; e += 2) {
      const int s0 = csr[e], s1 = csr[e + 1];
      const float4* rb0 = (const float4*)(bufB + s0 * STB + half * 16);
      const float4* rb1 = (const float4*)(bufB + s1 * STB + half * 16);
      const float4 p0 = rb0[0], p1 = rb0[1], p2 = rb0[2], p3 = rb0[3];
      const float4 q0 = rb1[0], q1 = rb1[1], q2 = rb1[2], q3 = rb1[3];
      A0.x += p0.x + q0.x; A0.y += p0.y + q0.y; A0.z += p0.z + q0.z; A0.w += p0.w + q0.w;
      A1.x += p1.x + q1.x; A1.y += p1.y + q1.y; A1.z += p1.z + q1.z; A1.w += p1.w + q1.w;
      A2.x += p2.x + q2.x; A2.y += p2.y + q2.y; A2.z += p2.z + q2.z; A2.w += p2.w + q2.w;
      A3.x += p3.x + q3.x; A3.y += p3.y + q3.y; A3.z += p3.z + q3.z; A3.w += p3.w + q3.w;
    }
    if (e < e1) {
      const int s = csr[e];
      const float4* rb = (const float4*)(bufB + s * STB + half * 16);
      const float4 r0 = rb[0], r1 = rb[1], r2 = rb[2], r3 = rb[3];
      A0.x += r0.x; A0.y += r0.y; A0.z += r0.z; A0.w += r0.w;
      A1.x += r1.x; A1.y += r1.y; A1.z += r1.z; A1.w += r1.w;
      A2.x += r2.x; A2.y += r2.y; A2.z += r2.z; A2.w += r2.w;
      A3.x += r3.x; A3.y += r3.y; A3.z += r3.z; A3.w += r3.w;
    }
    const float nv = nrm[u];
    h[0]=tanhf(A0.x*nv); h[1]=tanhf(A0.y*nv); h[2]=tanhf(A0.z*nv); h[3]=tanhf(A0.w*nv);
    h[4]=tanhf(A1.x*nv); h[5]=tanhf(A1.y*nv); h[6]=tanhf(A1.z*nv); h[7]=tanhf(A1.w*nv);
    h[8]=tanhf(A2.x*nv); h[9]=tanhf(A2.y*nv); h[10]=tanhf(A2.z*nv); h[11]=tanhf(A2.w*nv);
    h[12]=tanhf(A3.x*nv); h[13]=tanhf(A3.y*nv); h[14]=tanhf(A3.z*nv); h[15]=tanhf(A3.w*nv);
  };

  auto put_h = [&]() {                   // h -> bufB row u
    float4* br = (float4*)(bufB + u * STB + half * 16);
#pragma unroll
    for (int j = 0; j < 4; j++)
      br[j] = make_float4(h[j*4+0], h[j*4+1], h[j*4+2], h[j*4+3]);
  };

  // h1 archive: [pair][node u] float2 in the dead x-stage region (8 b64 writes)
  auto store_h1 = [&]() {
#pragma unroll
    for (int k = 0; k < 8; k++)
      stage2[(half * 8 + k) * 512 + u] = make_float2(h[2*k], h[2*k+1]);
  };

  // h2 archive: global, row-major per node u (full 128 B lines; only the top-64 gather reads it back)
  auto spill2 = [&]() {
    float4* dst = (float4*)(hs2 + (size_t)(nb + u) * 32 + half * 16);
#pragma unroll
    for (int j = 0; j < 4; j++)
      dst[j] = make_float4(h[j*4+0], h[j*4+1], h[j*4+2], h[j*4+3]);
  };

  // lin core (tid-keyed node v): hf[32] -> 16 outputs for own half -> bufB row v
  auto lin_core = [&](const float* hf, const float* __restrict__ W, const float* __restrict__ b) {
    float acc[16];
#pragma unroll
    for (int c = 0; c < 16; c++) {
      const int C = half * 16 + c;
      const float* wr = W + C * 32;
      float a = b[C];
#pragma unroll
      for (int j = 0; j < 32; j++) a = fmaf(hf[j], wr[j], a);
      acc[c] = a;
    }
    float4* br = (float4*)(bufB + v * STB + half * 16);
#pragma unroll
    for (int j = 0; j < 4; j++)
      br[j] = make_float4(acc[j*4+0], acc[j*4+1], acc[j*4+2], acc[j*4+3]);
  };

  // ---------- layers ----------
  do_agg();            // h1 for node u (reads bufB = z0)
  store_h1();          // h1 -> stage archive (disjoint region)
  __syncthreads();     // A: all agg reads of z0 + archive writes complete
  {                    // lin1 (node v): input h1 from stage pairs (16 b64), z1 -> bufB
    float hf[32];
#pragma unroll
    for (int p = 0; p < 16; p++) {
      const float2 t = stage2[p * 512 + v];
      hf[2*p] = t.x; hf[2*p+1] = t.y;
    }
    lin_core(hf, W1, b1);
  }
  __syncthreads();     // B: z1 rows complete
  do_agg();            // h2 for node u
  __syncthreads();     // C1: agg reads of z1 done -> safe to overwrite bufB
  put_h();             // h2 -> bufB row u (lin2 input, LDS — no global round-trip)
  spill2();            // h2 -> global row u (gather-only)
  __syncthreads();     // C2: bufB h2 rows complete
  {                    // lin2 (node v): input h2 from bufB row v, z2 -> bufB
    float hf[32];
    const float4* rr = (const float4*)(bufB + v * STB);
#pragma unroll
    for (int j = 0; j < 8; j++) {
      const float4 t = rr[j];
      hf[4*j]=t.x; hf[4*j+1]=t.y; hf[4*j+2]=t.z; hf[4*j+3]=t.w;
    }
    __syncthreads(); // C3: all row reads done before rewrite
    lin_core(hf, W2, b2);
  }
  __syncthreads();     // D: z2 rows complete
  do_agg();            // h3 for node u
  __syncthreads();     // E: agg reads of z2 done
  put_h();             // h3 -> bufB row u
  __syncthreads();     // F: h3 rows complete

  // ---------- layer 3 (1 ch, double acc — sort key); lin3 tid-keyed ----------
  if (tid < 512) {
    const float4* rr = (const float4*)(bufB + tid * STB);
    double a = (double)b3[0];
#pragma unroll
    for (int j = 0; j < 8; j++) {
      const float4 t = rr[j];
      a = fma((double)t.x, (double)W3[j*4+0], a);
      a = fma((double)t.y, (double)W3[j*4+1], a);
      a = fma((double)t.z, (double)W3[j*4+2], a);
      a = fma((double)t.w, (double)W3[j*4+3], a);
    }
    lin3S[tid] = (float)a;
  }
  __syncthreads();
  if (tid < 512) {     // h4 for node u (balanced loop); keyA overlays nrm (read-own-then-write-own)
    double a = (double)lin3S[u];
    const int e0 = offs[u], e1 = offs[u + 1];
    for (int e = e0; e < e1; e++) a += (double)lin3S[csr[e]];
    a *= (double)nrm[u];
    keyA[u] = tanhf((float)a);
  }
  __syncthreads();     // keyA visible; csr dead -> rankP may overlay csr

  // ---------- counting-rank selection (== stable argsort of -key, top-64) ----------
  {
    const int i = tid & 511;
    const int p = tid >> 9;
    const float ki = keyA[i];
    const float4* k4 = (const float4*)(keyA + p * 256);
    int cnt = 0;
#pragma unroll 8
    for (int jj = 0; jj < 64; jj++) {
      const float4 kv = k4[jj];          // wave-uniform -> LDS broadcast
      const int j0 = p * 256 + jj * 4;
      cnt += (kv.x > ki || (kv.x == ki && (j0    ) < i)) ? 1 : 0;
      cnt += (kv.y > ki || (kv.y == ki && (j0 + 1) < i)) ? 1 : 0;
      cnt += (kv.z > ki || (kv.z == ki && (j0 + 2) < i)) ? 1 : 0;
      cnt += (kv.w > ki || (kv.w == ki && (j0 + 3) < i)) ? 1 : 0;
    }
    rankP[tid] = (unsigned short)cnt;
  }
  __syncthreads();
  if (tid < 512) {
    const int r = (int)rankP[tid] + (int)rankP[tid + 512];
    if (r < 64) { topIdx[r] = (unsigned short)tid; topKey[r] = keyA[tid]; }
  }
  __syncthreads();

  // ---------- fused gather: read h1S/hs2/bufB(h3) -> regs, then featS (transposed) overlays bufB ----------
  // wave wv = dim-slot t, lane = node rank k; featS row k = 100 floats (400 B, 16B-aligned)
  {
    const int k = lane;                 // 0..63
    const int t = wv;                   // 0..15
    const int node = (int)topIdx[k];
    const float* h1f = stageF;          // pair-major: channel c at (c>>1)*1024 + node*2 + (c&1)
    const float a0 = h1f[ (t       >> 1) * 1024 + node * 2 + (t & 1)];        // h1 d = t
    const float a1 = h1f[(((t + 16) >> 1)) * 1024 + node * 2 + (t & 1)];      // h1 d = t+16
    const float* h2row = hs2 + (size_t)(nb + node) * 32;
    const float b0v = h2row[t];                              // h2 d = 32+t
    const float b1v = h2row[t + 16];                         // h2 d = 48+t
    const float* brow = bufB + node * STB;
    const float c0v = brow[t];                               // h3 d = 64+t
    const float c1v = brow[t + 16];                          // h3 d = 80+t
    const float kk = topKey[k];                              // h4 d = 96
    __syncthreads();                    // bufB reads complete -> safe to overlay
    float* fr = bufB + FO_FEAT + k * 100;
    fr[t     ] = a0;
    fr[t + 16] = a1;
    fr[t + 32] = b0v;
    fr[t + 48] = b1v;
    fr[t + 64] = c0v;
    fr[t + 80] = c1v;
    if (t == 0) fr[96] = kk;
  }
  __syncthreads();

  // ---------- conv1 (per-node linear over 97) + maxpool(2,2) fused via wave shuffles ----------
  // featS row-major: thread reads own node row via 24 b128 + 1 b32 (8 start groups x 8 lanes = floor)
  {
    const float* fr = bufB + FO_FEAT + lane * 100;
    float* ps = bufB + FO_P;
    const int ch = wv;           // 0..15
    float a = c1b[ch];
    const float* wr = c1w + ch * 97;
#pragma unroll
    for (int j = 0; j < 24; j++) {
      const float4 t4 = *(const float4*)(fr + j * 4);
      a = fmaf(t4.x, wr[j*4+0], a);
      a = fmaf(t4.y, wr[j*4+1], a);
      a = fmaf(t4.z, wr[j*4+2], a);
      a = fmaf(t4.w, wr[j*4+3], a);
    }
    a = fmaf(fr[96], wr[96], a);
    a = fmaxf(a, 0.f);                                // c1[ch][lane]
    const float m  = fmaxf(a, __shfl_down(a, 1, 64)); // valid at even lanes
    const float pv = __shfl(m, (lane & 31) * 2, 64);  // pool pair (2jj, 2jj+1)
    if (lane < 32) ps[ch * 32 + lane] = pv;
  }
  __syncthreads();

  // ---------- conv2 (k=5, valid): wave = 2 out channels ----------
  {
    const float* ps  = bufB + FO_P;
    float* c2s = bufB + FO_C2;
    const int o = wv;            // and o+16
    if (lane < 28) {
      float a0 = 0.f, a1 = 0.f;
      for (int i = 0; i < 16; i++) {
#pragma unroll
        for (int r = 0; r < 5; r++) {
          const float pv = ps[i * 32 + lane + r];
          a0 = fmaf(pv, c2w[((o     ) * 16 + i) * 5 + r], a0);
          a1 = fmaf(pv, c2w[((o + 16) * 16 + i) * 5 + r], a1);
        }
      }
      c2s[(o     ) * 28 + lane] = fmaxf(a0 + c2b[o     ], 0.f);
      c2s[(o + 16) * 28 + lane] = fmaxf(a1 + c2b[o + 16], 0.f);
    }
  }
  __syncthreads();

  // ---------- d1: 896 -> 128 relu; wave computes 8 outputs ----------
  {
    const float* c2s  = bufB + FO_C2;
    float* hids = bufB + FO_HID;
    float fl[14];
#pragma unroll
    for (int j = 0; j < 14; j++) fl[j] = c2s[lane + j * 64];
#pragma unroll 2
    for (int hh = 0; hh < 8; hh++) {
      const int hI = wv * 8 + hh;
      const float* wr = d1w + (size_t)hI * 896;
      float a = 0.f;
#pragma unroll
      for (int j = 0; j < 14; j++) a = fmaf(fl[j], wr[lane + j * 64], a);
#pragma unroll
      for (int m = 32; m > 0; m >>= 1) a += __shfl_xor(a, m, 64);
      if (lane == 0) hids[hI] = fmaxf(a + d1b[hI], 0.f);
    }
  }
  __syncthreads();

  // ---------- d2: 128 -> 10 ----------
  if (tid < 10) {
    const float* hids = bufB + FO_HID;
    const float* wr = d2w + tid * 128;
    double a = (double)d2b[tid];
#pragma unroll 8
    for (int hh = 0; hh < 128; hh++) a = fma((double)hids[hh], (double)wr[hh], a);
    out[g * 10 + tid] = (float)a;
  }
}

extern "C" void kernel_launch(void* const* d_in, const int* in_sizes, int n_in,
                              void* d_out, int out_size, void* d_ws, size_t ws_size,
                              hipStream_t stream) {
  const float* x   = (const float*)d_in[0];
  const float* W0  = (const float*)d_in[1];
  const float* b0  = (const float*)d_in[2];
  const float* W1  = (const float*)d_in[3];
  const float* b1  = (const float*)d_in[4];
  const float* W2  = (const float*)d_in[5];
  const float* b2  = (const float*)d_in[6];
  const float* W3  = (const float*)d_in[7];
  const float* b3  = (const float*)d_in[8];
  const float* c1w = (const float*)d_in[9];
  const float* c1b = (const float*)d_in[10];
  const float* c2w = (const float*)d_in[11];
  const float* c2b = (const float*)d_in[12];
  const float* d1w = (const float*)d_in[13];
  const float* d1b = (const float*)d_in[14];
  const float* d2w = (const float*)d_in[15];
  const float* d2b = (const float*)d_in[16];
  const int* esrc  = (const int*)d_in[17];
  const int* edst  = (const int*)d_in[18];

  float* hs2 = (float*)d_ws;                       // 256*512*32 f32 = 16 MB
  float* outp = (float*)d_out;

  hipFuncSetAttribute(reinterpret_cast<const void*>(dgcnn_fused),
                      hipFuncAttributeMaxDynamicSharedMemorySize, SMEM_SZ);
  dgcnn_fused<<<NG, 1024, SMEM_SZ, stream>>>(x, W0, b0, W1, b1, W2, b2, W3, b3,
                                             c1w, c1b, c2w, c2b, d1w, d1b, d2w, d2b,
                                             esrc, edst, hs2, outp);
}

// Round 10
// 271.831 us; speedup vs baseline: 1.0316x; 1.0316x over previous
//
#include <hip/hip_runtime.h>

#define NG   256   // graphs (= grid)
#define NP   512   // nodes per graph
#define EPG  8192  // edges per graph
#define FDIM 128
#define STB  36    // bufB stride (floats): 144 B, 16B-aligned; random-row b128 gather at its throughput floor

// ---- LDS layout (bytes) ----
#define OFF_STAGE 0                        // x chunk stage: 512 rows x 128 B = 65536; later h1 archive [16 pairs][512] float2
#define OFF_BUFB  65536                    // f32[512*36] = 73728 -> ends 139264
#define OFF_CSR   139264                   // u16[8192] = 16384 -> 155648
#define OFF_OFFS  155648                   // u16[513] -> 1032  -> 156680
#define OFF_WT    156680                   // u32[8] = 32       -> 156712
#define OFF_CUR   156712                   // u32[512] = 2048   -> 158760 (lin3S overlay later)
#define OFF_PAD   158760                   // 8 B pad
#define OFF_DCNT  158768                   // u32[512] = 2048   -> 160816
#define OFF_NRM   160816                   // f32[512] = 2048   -> 162864 (keyA overlay after h4)
#define OFF_BINS  162864                   // u32[96]: [0..47] counts, [48..95] excl offsets -> 163248
#define SMEM_SZ   163248                   // <= 163840

// overlays
#define OFF_L3    OFF_CUR                  // f32[512] lin3S (cursors dead after CSR build)
#define OFF_PERM  OFF_DCNT                 // u16[512] degree-balanced perm (dcnt dead after PH2a)
#define OFF_KEY   OFF_NRM                  // f32[512] keyA (each slot read-own-then-write-own in h4)
#define OFF_RANKP OFF_CSR                  // u16[1024] (csr dead after h4 agg)
#define OFF_TIDX  (OFF_CSR + 2048)         // u16[64] (pad to 256)
#define OFF_TKEY  (OFF_CSR + 2304)         // f32[64]
// tail arrays overlay bufB (h3 consumed by fused gather before overwrite); float offsets
// featS transposed: [64 nodes][100 floats] (stride 100 = 400 B, 16B-aligned rows; 8 start groups)
#define FO_FEAT 0                          // f32[64*100] = 6400 floats
#define FO_P    6400                       // f32[16*32]
#define FO_C2   6912                       // f32[896]
#define FO_HID  7808                       // f32[128]

__global__ __launch_bounds__(1024, 4) void dgcnn_fused(
    const float* __restrict__ x,
    const float* __restrict__ W0, const float* __restrict__ b0,
    const float* __restrict__ W1, const float* __restrict__ b1,
    const float* __restrict__ W2, const float* __restrict__ b2,
    const float* __restrict__ W3, const float* __restrict__ b3,
    const float* __restrict__ c1w, const float* __restrict__ c1b,
    const float* __restrict__ c2w, const float* __restrict__ c2b,
    const float* __restrict__ d1w, const float* __restrict__ d1b,
    const float* __restrict__ d2w, const float* __restrict__ d2b,
    const int* __restrict__ esrc, const int* __restrict__ edst,
    float* __restrict__ hs2,
    float* __restrict__ out)
{
  extern __shared__ char smem[];
  float*          stageF = (float*)(smem + OFF_STAGE);
  float2*         stage2 = (float2*)(smem + OFF_STAGE);   // h1 archive pair view
  float*          bufB  = (float*)(smem + OFF_BUFB);
  unsigned short* csr   = (unsigned short*)(smem + OFF_CSR);
  unsigned short* offs  = (unsigned short*)(smem + OFF_OFFS);
  unsigned int*   wt    = (unsigned int*)(smem + OFF_WT);
  unsigned int*   cur   = (unsigned int*)(smem + OFF_CUR);
  unsigned int*   dcnt  = (unsigned int*)(smem + OFF_DCNT);
  float*          nrm   = (float*)(smem + OFF_NRM);
  unsigned int*   bins  = (unsigned int*)(smem + OFF_BINS);
  unsigned short* perm  = (unsigned short*)(smem + OFF_PERM);
  float*          lin3S = (float*)(smem + OFF_L3);
  float*          keyA  = (float*)(smem + OFF_KEY);
  unsigned short* rankP = (unsigned short*)(smem + OFF_RANKP);
  unsigned short* topIdx= (unsigned short*)(smem + OFF_TIDX);
  float*          topKey= (float*)(smem + OFF_TKEY);

  const int g    = blockIdx.x;
  const int tid  = threadIdx.x;
  const int lane = tid & 63;
  const int wv   = __builtin_amdgcn_readfirstlane(tid >> 6);   // 0..15, wave-uniform
  const int half = __builtin_amdgcn_readfirstlane(tid >> 9);   // 0/1, wave-uniform
  const int v    = tid & 511;                                  // tid-keyed node (lin/archive-read/gather)
  const int nb   = g * NP;

  // x chunk loaders: chunk kc = dims [kc*32, kc*32+32) for all 512 rows.
  const int ldRow0 = tid >> 3;
  const int ldGrp  = tid & 7;
  const int ldSwz  = (ldGrp ^ (ldRow0 & 7)) * 16;   // row&7 invariant under +128
  auto load_chunk = [&](int kc, float4* xr) {
    const float* base = x + (size_t)nb * FDIM + kc * 32 + ldGrp * 4;
#pragma unroll
    for (int it = 0; it < 4; it++)
      xr[it] = *(const float4*)(base + (size_t)(ldRow0 + it * 128) * FDIM);
  };
  auto store_chunk = [&](const float4* xr) {
#pragma unroll
    for (int it = 0; it < 4; it++)
      *(float4*)(smem + OFF_STAGE + (ldRow0 + it * 128) * 128 + ldSwz) = xr[it];
  };

  // ---------- issue x chunk0 first (needed at first store), then edges ----------
  float4 xr[4], xr2[4];
  load_chunk(0, xr);
  const int eb = g * EPG;
  const int4* s4p = (const int4*)(esrc + eb);
  const int4* d4p = (const int4*)(edst + eb);
  const int4 sa = s4p[tid], sb = s4p[tid + 1024];
  const int4 da = d4p[tid], db = d4p[tid + 1024];

  int es[8], ed[8];
  es[0]=sa.x-nb; es[1]=sa.y-nb; es[2]=sa.z-nb; es[3]=sa.w-nb;
  es[4]=sb.x-nb; es[5]=sb.y-nb; es[6]=sb.z-nb; es[7]=sb.w-nb;
  ed[0]=da.x-nb; ed[1]=da.y-nb; ed[2]=da.z-nb; ed[3]=da.w-nb;
  ed[4]=db.x-nb; ed[5]=db.y-nb; ed[6]=db.z-nb; ed[7]=db.w-nb;

  // ---------- zero counters (ordered by S2 barrier; disjoint from stage writes) ----------
  if (tid < 512) { cur[tid] = 0u; dcnt[tid] = 0u; }
  if (tid < 96)  bins[tid] = 0u;

  // ---------- lin0 with CSR-build phases woven into chunk slots ----------
  float acc0[16];
#pragma unroll
  for (int c = 0; c < 16; c++) acc0[c] = b0[half * 16 + c];
  const char* rowp = smem + OFF_STAGE + v * 128;
  const int vswz = v & 7;
  int mydeg = 0;

  auto compute_chunk = [&](const int kc) {
#pragma unroll
    for (int jg = 0; jg < 8; jg++) {
      const float4 t = *(const float4*)(rowp + ((jg ^ vswz) * 16));
#pragma unroll
      for (int c = 0; c < 16; c++) {
        const float* wr = W0 + (size_t)(half * 16 + c) * FDIM + kc * 32 + jg * 4;
        acc0[c] = fmaf(t.x, wr[0], acc0[c]);
        acc0[c] = fmaf(t.y, wr[1], acc0[c]);
        acc0[c] = fmaf(t.z, wr[2], acc0[c]);
        acc0[c] = fmaf(t.w, wr[3], acc0[c]);
      }
    }
  };

  // ---- kc = 0 ----
  store_chunk(xr);
  load_chunk(1, xr2);
  __syncthreads();                       // S2: stage0 + zeroed counters visible
  // PH1: degree counts (edge latency hidden under chunk0 staging)
#pragma unroll
  for (int i = 0; i < 8; i++) {
    atomicAdd(&dcnt[es[i]], 1u);        // out-degree (low 16)
    atomicAdd(&dcnt[ed[i]], 65536u);    // in-degree  (high 16)
  }
  compute_chunk(0);
#pragma unroll
  for (int it = 0; it < 4; it++) xr[it] = xr2[it];
  __syncthreads();                       // S3: stage reads done, dcnt complete
  // ---- kc = 1 ----
  store_chunk(xr);
  load_chunk(2, xr2);
  __syncthreads();                       // S4: stage1 ready
  // PH2a: norm + wave-shuffle scan of in-degree
  unsigned c_scan = 0;
  if (tid < 512) {
    const unsigned cw = dcnt[tid];
    nrm[tid] = 1.0f / (float)((cw & 0xFFFFu) + 1u);
    c_scan = cw >> 16;
    mydeg = (int)(cw >> 16);
    for (int d = 1; d < 64; d <<= 1) {
      const unsigned t = __shfl_up(c_scan, (unsigned)d, 64);
      if (lane >= d) c_scan += t;
    }
    if (lane == 63) wt[wv] = c_scan;
  }
  compute_chunk(1);
#pragma unroll
  for (int it = 0; it < 4; it++) xr[it] = xr2[it];
  __syncthreads();                       // S5: stage reads done, wt visible
  // ---- kc = 2 ----
  store_chunk(xr);
  load_chunk(3, xr2);
  __syncthreads();                       // S6: stage2 ready
  // PH2b: exclusive offsets + degree-bin counts
  if (tid < 512) {
    unsigned base = 0;
    for (int w = 0; w < wv; w++) base += wt[w];
    offs[tid + 1] = (unsigned short)(base + c_scan);
    if (tid == 0) offs[0] = 0;
    const int dd = mydeg > 47 ? 47 : mydeg;
    atomicAdd(&bins[dd], 1u);
  }
  compute_chunk(2);
  __syncthreads();                       // S7: stage reads done, offs + bins visible
  // ---- kc = 3 ----
  store_chunk(xr2);
  __syncthreads();                       // S8: stage3 ready
  // PH3: fill CSR (src bucketed by dst)
#pragma unroll
  for (int i = 0; i < 8; i++) {
    const unsigned pos = (unsigned)offs[ed[i]] + atomicAdd(&cur[ed[i]], 1u);
    csr[pos] = (unsigned short)es[i];
  }
  // bin exclusive scan (wave 15; bins counted complete since S7)
  if (wv == 15) {
    const unsigned bc = (lane < 48) ? bins[lane] : 0u;
    unsigned sc = bc;
    for (int d = 1; d < 64; d <<= 1) {
      const unsigned t2 = __shfl_up(sc, (unsigned)d, 64);
      if (lane >= d) sc += t2;
    }
    if (lane < 48) bins[48 + lane] = sc - bc;   // exclusive offset
  }
  compute_chunk(3);
  {
    float4* br = (float4*)(bufB + v * STB + half * 16);
#pragma unroll
    for (int j = 0; j < 4; j++)
      br[j] = make_float4(acc0[j*4+0], acc0[j*4+1], acc0[j*4+2], acc0[j*4+3]);
  }
  __syncthreads();                       // S9: csr + bufB(z0) + bin offsets complete

  // ---------- degree-balanced permutation: thread i <-> node perm[i]; waves get uniform degree ----------
  if (tid < 512) {
    const int dd = mydeg > 47 ? 47 : mydeg;
    const unsigned c = atomicSub(&bins[dd], 1u);        // returns old count
    perm[bins[48 + dd] + c - 1u] = (unsigned short)tid; // bijective placement
  }
  __syncthreads();                       // S9b: perm complete
  const int u = (int)perm[v];            // agg-keyed node (both halves of a node read same slot)

  // aggregate own half (16 ch) for node u: h = tanh(nrm * (self + sum_neigh))
  // 4-row batching + csr index software-pipeline; per-node add order identical to round-4..8.
  float h[16];
  auto do_agg = [&]() {
    float4 A0, A1, A2, A3;
    const float4* sr = (const float4*)(bufB + u * STB + half * 16);
    A0 = sr[0]; A1 = sr[1]; A2 = sr[2]; A3 = sr[3];
    const int e0 = offs[u], e1 = offs[u + 1];
    int e = e0;
    int sc0 = 0, sc1 = 0, sc2 = 0, sc3 = 0;
    if (e + 3 < e1) { sc0 = csr[e]; sc1 = csr[e+1]; sc2 = csr[e+2]; sc3 = csr[e+3]; }
    while (e + 3 < e1) {
      const int s0 = sc0, s1 = sc1, s2 = sc2, s3 = sc3;
      const int en = e + 4;
      if (en + 3 < e1) { sc0 = csr[en]; sc1 = csr[en+1]; sc2 = csr[en+2]; sc3 = csr[en+3]; }
      const float4* rb0 = (const float4*)(bufB + s0 * STB + half * 16);
      const float4* rb1 = (const float4*)(bufB + s1 * STB + half * 16);
      const float4* rb2 = (const float4*)(bufB + s2 * STB + half * 16);
      const float4* rb3 = (const float4*)(bufB + s3 * STB + half * 16);
      const float4 p0 = rb0[0], p1 = rb0[1], p2 = rb0[2], p3 = rb0[3];
      const float4 q0 = rb1[0], q1 = rb1[1], q2 = rb1[2], q3 = rb1[3];
      const float4 r0 = rb2[0], r1 = rb2[1], r2 = rb2[2], r3 = rb2[3];
      const float4 t0 = rb3[0], t1 = rb3[1], t2 = rb3[2], t3 = rb3[3];
      // pair 1
      A0.x += p0.x + q0.x; A0.y += p0.y + q0.y; A0.z += p0.z + q0.z; A0.w += p0.w + q0.w;
      A1.x += p1.x + q1.x; A1.y += p1.y + q1.y; A1.z += p1.z + q1.z; A1.w += p1.w + q1.w;
      A2.x += p2.x + q2.x; A2.y += p2.y + q2.y; A2.z += p2.z + q2.z; A2.w += p2.w + q2.w;
      A3.x += p3.x + q3.x; A3.y += p3.y + q3.y; A3.z += p3.z + q3.z; A3.w += p3.w + q3.w;
      // pair 2
      A0.x += r0.x + t0.x; A0.y += r0.y + t0.y; A0.z += r0.z + t0.z; A0.w += r0.w + t0.w;
      A1.x += r1.x + t1.x; A1.y += r1.y + t1.y; A1.z += r1.z + t1.z; A1.w += r1.w + t1.w;
      A2.x += r2.x + t2.x; A2.y += r2.y + t2.y; A2.z += r2.z + t2.z; A2.w += r2.w + t2.w;
      A3.x += r3.x + t3.x; A3.y += r3.y + t3.y; A3.z += r3.z + t3.z; A3.w += r3.w + t3.w;
      e = en;
    }
    for (; e + 1 < e1; e += 2) {
      const int s0 = csr[e], s1 = csr[e + 1];
      const float4* rb0 = (const float4*)(bufB + s0 * STB + half * 16);
      const float4* rb1 = (const float4*)(bufB + s1 * STB + half * 16);
      const float4 p0 = rb0[0], p1 = rb0[1], p2 = rb0[2], p3 = rb0[3];
      const float4 q0 = rb1[0], q1 = rb1[1], q2 = rb1[2], q3 = rb1[3];
      A0.x += p0.x + q0.x; A0.y += p0.y + q0.y; A0.z += p0.z + q0.z; A0.w += p0.w + q0.w;
      A1.x += p1.x + q1.x; A1.y += p1.y + q1.y; A1.z += p1.z + q1.z; A1.w += p1.w + q1.w;
      A2.x += p2.x + q2.x; A2.y += p2.y + q2.y; A2.z += p2.z + q2.z; A2.w += p2.w + q2.w;
      A3.x += p3.x + q3.x; A3.y += p3.y + q3.y; A3.z += p3.z + q3.z; A3.w += p3.w + q3.w;
    }
    if (e < e1) {
      const int s = csr[e];
      const float4* rb = (const float4*)(bufB + s * STB + half * 16);
      const float4 r0 = rb[0], r1 = rb[1], r2 = rb[2], r3 = rb[3];
      A0.x += r0.x; A0.y += r0.y; A0.z += r0.z; A0.w += r0.w;
      A1.x += r1.x; A1.y += r1.y; A1.z += r1.z; A1.w += r1.w;
      A2.x += r2.x; A2.y += r2.y; A2.z += r2.z; A2.w += r2.w;
      A3.x += r3.x; A3.y += r3.y; A3.z += r3.z; A3.w += r3.w;
    }
    const float nv = nrm[u];
    h[0]=tanhf(A0.x*nv); h[1]=tanhf(A0.y*nv); h[2]=tanhf(A0.z*nv); h[3]=tanhf(A0.w*nv);
    h[4]=tanhf(A1.x*nv); h[5]=tanhf(A1.y*nv); h[6]=tanhf(A1.z*nv); h[7]=tanhf(A1.w*nv);
    h[8]=tanhf(A2.x*nv); h[9]=tanhf(A2.y*nv); h[10]=tanhf(A2.z*nv); h[11]=tanhf(A2.w*nv);
    h[12]=tanhf(A3.x*nv); h[13]=tanhf(A3.y*nv); h[14]=tanhf(A3.z*nv); h[15]=tanhf(A3.w*nv);
  };

  auto put_h = [&]() {                   // h -> bufB row u
    float4* br = (float4*)(bufB + u * STB + half * 16);
#pragma unroll
    for (int j = 0; j < 4; j++)
      br[j] = make_float4(h[j*4+0], h[j*4+1], h[j*4+2], h[j*4+3]);
  };

  // h1 archive: [pair][node u] float2 in the dead x-stage region (8 b64 writes)
  auto store_h1 = [&]() {
#pragma unroll
    for (int k = 0; k < 8; k++)
      stage2[(half * 8 + k) * 512 + u] = make_float2(h[2*k], h[2*k+1]);
  };

  // h2 archive: global, row-major per node u (full 128 B lines; lin2 + gather read it back)
  auto spill2 = [&]() {
    float4* dst = (float4*)(hs2 + (size_t)(nb + u) * 32 + half * 16);
#pragma unroll
    for (int j = 0; j < 4; j++)
      dst[j] = make_float4(h[j*4+0], h[j*4+1], h[j*4+2], h[j*4+3]);
  };

  // lin core (tid-keyed node v): hf[32] -> 16 outputs for own half -> bufB row v
  auto lin_core = [&](const float* hf, const float* __restrict__ W, const float* __restrict__ b) {
    float acc[16];
#pragma unroll
    for (int c = 0; c < 16; c++) {
      const int C = half * 16 + c;
      const float* wr = W + C * 32;
      float a = b[C];
#pragma unroll
      for (int j = 0; j < 32; j++) a = fmaf(hf[j], wr[j], a);
      acc[c] = a;
    }
    float4* br = (float4*)(bufB + v * STB + half * 16);
#pragma unroll
    for (int j = 0; j < 4; j++)
      br[j] = make_float4(acc[j*4+0], acc[j*4+1], acc[j*4+2], acc[j*4+3]);
  };

  // ---------- layers ----------
  do_agg();            // h1 for node u (reads bufB = z0)
  store_h1();          // h1 -> stage archive (disjoint region)
  __syncthreads();     // A: all agg reads of z0 + archive writes complete
  {                    // lin1 (node v): input h1 from stage pairs (16 b64), z1 -> bufB
    float hf[32];
#pragma unroll
    for (int p = 0; p < 16; p++) {
      const float2 t = stage2[p * 512 + v];
      hf[2*p] = t.x; hf[2*p+1] = t.y;
    }
    lin_core(hf, W1, b1);
  }
  __syncthreads();     // B: z1 rows complete
  do_agg();            // h2 for node u
  spill2();            // h2 -> global row u
  __syncthreads();     // C: agg reads of z1 done; hs2 writes drained
  {                    // lin2 (node v): input h2 from hs2 row v (L2-resident), z2 -> bufB
    float hf[32];
    const float4* rr = (const float4*)(hs2 + (size_t)(nb + v) * 32);
#pragma unroll
    for (int j = 0; j < 8; j++) {
      const float4 t = rr[j];
      hf[4*j]=t.x; hf[4*j+1]=t.y; hf[4*j+2]=t.z; hf[4*j+3]=t.w;
    }
    lin_core(hf, W2, b2);
  }
  __syncthreads();     // D: z2 rows complete
  do_agg();            // h3 for node u
  __syncthreads();     // E: agg reads of z2 done
  put_h();             // h3 -> bufB row u
  __syncthreads();     // F: h3 rows complete

  // ---------- layer 3 (1 ch, double acc — sort key); lin3 tid-keyed ----------
  if (tid < 512) {
    const float4* rr = (const float4*)(bufB + tid * STB);
    double a = (double)b3[0];
#pragma unroll
    for (int j = 0; j < 8; j++) {
      const float4 t = rr[j];
      a = fma((double)t.x, (double)W3[j*4+0], a);
      a = fma((double)t.y, (double)W3[j*4+1], a);
      a = fma((double)t.z, (double)W3[j*4+2], a);
      a = fma((double)t.w, (double)W3[j*4+3], a);
    }
    lin3S[tid] = (float)a;
  }
  __syncthreads();
  if (tid < 512) {     // h4 for node u (balanced loop); keyA overlays nrm (read-own-then-write-own)
    double a = (double)lin3S[u];
    const int e0 = offs[u], e1 = offs[u + 1];
    for (int e = e0; e < e1; e++) a += (double)lin3S[csr[e]];
    a *= (double)nrm[u];
    keyA[u] = tanhf((float)a);
  }
  __syncthreads();     // keyA visible; csr dead -> rankP may overlay csr

  // ---------- counting-rank selection (== stable argsort of -key, top-64) ----------
  {
    const int i = tid & 511;
    const int p = tid >> 9;
    const float ki = keyA[i];
    const float4* k4 = (const float4*)(keyA + p * 256);
    int cnt = 0;
#pragma unroll 8
    for (int jj = 0; jj < 64; jj++) {
      const float4 kv = k4[jj];          // wave-uniform -> LDS broadcast
      const int j0 = p * 256 + jj * 4;
      cnt += (kv.x > ki || (kv.x == ki && (j0    ) < i)) ? 1 : 0;
      cnt += (kv.y > ki || (kv.y == ki && (j0 + 1) < i)) ? 1 : 0;
      cnt += (kv.z > ki || (kv.z == ki && (j0 + 2) < i)) ? 1 : 0;
      cnt += (kv.w > ki || (kv.w == ki && (j0 + 3) < i)) ? 1 : 0;
    }
    rankP[tid] = (unsigned short)cnt;
  }
  __syncthreads();
  if (tid < 512) {
    const int r = (int)rankP[tid] + (int)rankP[tid + 512];
    if (r < 64) { topIdx[r] = (unsigned short)tid; topKey[r] = keyA[tid]; }
  }
  __syncthreads();

  // ---------- fused gather: read h1S/hs2/bufB(h3) -> regs, then featS (transposed) overlays bufB ----------
  // wave wv = dim-slot t, lane = node rank k; featS row k = 100 floats (400 B, 16B-aligned)
  {
    const int k = lane;                 // 0..63
    const int t = wv;                   // 0..15
    const int node = (int)topIdx[k];
    const float* h1f = stageF;          // pair-major: channel c at (c>>1)*1024 + node*2 + (c&1)
    const float a0 = h1f[ (t       >> 1) * 1024 + node * 2 + (t & 1)];        // h1 d = t
    const float a1 = h1f[(((t + 16) >> 1)) * 1024 + node * 2 + (t & 1)];      // h1 d = t+16
    const float* h2row = hs2 + (size_t)(nb + node) * 32;
    const float b0v = h2row[t];                              // h2 d = 32+t
    const float b1v = h2row[t + 16];                         // h2 d = 48+t
    const float* brow = bufB + node * STB;
    const float c0v = brow[t];                               // h3 d = 64+t
    const float c1v = brow[t + 16];                          // h3 d = 80+t
    const float kk = topKey[k];                              // h4 d = 96
    __syncthreads();                    // bufB reads complete -> safe to overlay
    float* fr = bufB + FO_FEAT + k * 100;
    fr[t     ] = a0;
    fr[t + 16] = a1;
    fr[t + 32] = b0v;
    fr[t + 48] = b1v;
    fr[t + 64] = c0v;
    fr[t + 80] = c1v;
    if (t == 0) fr[96] = kk;
  }
  __syncthreads();

  // ---------- conv1 (per-node linear over 97) + maxpool(2,2) fused via wave shuffles ----------
  // featS row-major: thread reads own node row via 24 b128 + 1 b32 (8 start groups x 8 lanes = floor)
  {
    const float* fr = bufB + FO_FEAT + lane * 100;
    float* ps = bufB + FO_P;
    const int ch = wv;           // 0..15
    float a = c1b[ch];
    const float* wr = c1w + ch * 97;
#pragma unroll
    for (int j = 0; j < 24; j++) {
      const float4 t4 = *(const float4*)(fr + j * 4);
      a = fmaf(t4.x, wr[j*4+0], a);
      a = fmaf(t4.y, wr[j*4+1], a);
      a = fmaf(t4.z, wr[j*4+2], a);
      a = fmaf(t4.w, wr[j*4+3], a);
    }
    a = fmaf(fr[96], wr[96], a);
    a = fmaxf(a, 0.f);                                // c1[ch][lane]
    const float m  = fmaxf(a, __shfl_down(a, 1, 64)); // valid at even lanes
    const float pv = __shfl(m, (lane & 31) * 2, 64);  // pool pair (2jj, 2jj+1)
    if (lane < 32) ps[ch * 32 + lane] = pv;
  }
  __syncthreads();

  // ---------- conv2 (k=5, valid): wave = 2 out channels ----------
  {
    const float* ps  = bufB + FO_P;
    float* c2s = bufB + FO_C2;
    const int o = wv;            // and o+16
    if (lane < 28) {
      float a0 = 0.f, a1 = 0.f;
      for (int i = 0; i < 16; i++) {
#pragma unroll
        for (int r = 0; r < 5; r++) {
          const float pv = ps[i * 32 + lane + r];
          a0 = fmaf(pv, c2w[((o     ) * 16 + i) * 5 + r], a0);
          a1 = fmaf(pv, c2w[((o + 16) * 16 + i) * 5 + r], a1);
        }
      }
      c2s[(o     ) * 28 + lane] = fmaxf(a0 + c2b[o     ], 0.f);
      c2s[(o + 16) * 28 + lane] = fmaxf(a1 + c2b[o + 16], 0.f);
    }
  }
  __syncthreads();

  // ---------- d1: 896 -> 128 relu; wave computes 8 outputs ----------
  {
    const float* c2s  = bufB + FO_C2;
    float* hids = bufB + FO_HID;
    float fl[14];
#pragma unroll
    for (int j = 0; j < 14; j++) fl[j] = c2s[lane + j * 64];
#pragma unroll 2
    for (int hh = 0; hh < 8; hh++) {
      const int hI = wv * 8 + hh;
      const float* wr = d1w + (size_t)hI * 896;
      float a = 0.f;
#pragma unroll
      for (int j = 0; j < 14; j++) a = fmaf(fl[j], wr[lane + j * 64], a);
#pragma unroll
      for (int m = 32; m > 0; m >>= 1) a += __shfl_xor(a, m, 64);
      if (lane == 0) hids[hI] = fmaxf(a + d1b[hI], 0.f);
    }
  }
  __syncthreads();

  // ---------- d2: 128 -> 10 ----------
  if (tid < 10) {
    const float* hids = bufB + FO_HID;
    const float* wr = d2w + tid * 128;
    double a = (double)d2b[tid];
#pragma unroll 8
    for (int hh = 0; hh < 128; hh++) a = fma((double)hids[hh], (double)wr[hh], a);
    out[g * 10 + tid] = (float)a;
  }
}

extern "C" void kernel_launch(void* const* d_in, const int* in_sizes, int n_in,
                              void* d_out, int out_size, void* d_ws, size_t ws_size,
                              hipStream_t stream) {
  const float* x   = (const float*)d_in[0];
  const float* W0  = (const float*)d_in[1];
  const float* b0  = (const float*)d_in[2];
  const float* W1  = (const float*)d_in[3];
  const float* b1  = (const float*)d_in[4];
  const float* W2  = (const float*)d_in[5];
  const float* b2  = (const float*)d_in[6];
  const float* W3  = (const float*)d_in[7];
  const float* b3  = (const float*)d_in[8];
  const float* c1w = (const float*)d_in[9];
  const float* c1b = (const float*)d_in[10];
  const float* c2w = (const float*)d_in[11];
  const float* c2b = (const float*)d_in[12];
  const float* d1w = (const float*)d_in[13];
  const float* d1b = (const float*)d_in[14];
  const float* d2w = (const float*)d_in[15];
  const float* d2b = (const float*)d_in[16];
  const int* esrc  = (const int*)d_in[17];
  const int* edst  = (const int*)d_in[18];

  float* hs2 = (float*)d_ws;                       // 256*512*32 f32 = 16 MB
  float* outp = (float*)d_out;

  hipFuncSetAttribute(reinterpret_cast<const void*>(dgcnn_fused),
                      hipFuncAttributeMaxDynamicSharedMemorySize, SMEM_SZ);
  dgcnn_fused<<<NG, 1024, SMEM_SZ, stream>>>(x, W0, b0, W1, b1, W2, b2, W3, b3,
                                             c1w, c1b, c2w, c2b, d1w, d1b, d2w, d2b,
                                             esrc, edst, hs2, outp);
}